// Round 1
// baseline (65211.914 us; speedup 1.0000x reference)
//
#include <hip/hip_runtime.h>
#include <math.h>

// Problem: T=2048, B=16, D=1024
//   Wx_all[t,b,e] = sum_d x[t,b,d] * W_x[e,d] + b[e]
//   scan: pre = h @ W_h^T + wx_t ; h += alpha*tanh(pre) ; out = h^2 * sigmoid(h)
// d_out layout: outs [T,B,D] floats, then h [T+1,B,D] floats.
// Trick: outs region is used as the Wx_all buffer; step t reads wx[t] and
// overwrites the same slab with out[t].

#define T_STEPS 2048
#define BATCH 16
#define DIM 1024

// ---------------- GEMM: C[m,n] = sum_k X[m,k]*W[n,k] + bias[n] ----------------
// M=32768, N=K=1024. 64x64 tile, 16-deep k-tile, 256 threads, 4x4 microtile.
__global__ __launch_bounds__(256) void gemm_wx_kernel(
    const float* __restrict__ X,     // [M, K]
    const float* __restrict__ W,     // [N, K]
    const float* __restrict__ bias,  // [N]
    float* __restrict__ C)           // [M, N]
{
    const int K = DIM, N = DIM;
    __shared__ float Xs[64][17];
    __shared__ float Ws[64][17];
    const int tid = threadIdx.x;
    const int m0 = blockIdx.x * 64;
    const int n0 = blockIdx.y * 64;
    const int ty = tid >> 4;     // 0..15
    const int tx = tid & 15;     // 0..15
    float acc[4][4] = {};

    for (int k0 = 0; k0 < K; k0 += 16) {
#pragma unroll
        for (int i = 0; i < 4; i++) {
            int idx = tid + i * 256;
            int r = idx >> 4;
            int c = idx & 15;
            Xs[r][c] = X[(size_t)(m0 + r) * K + (k0 + c)];
            Ws[r][c] = W[(size_t)(n0 + r) * K + (k0 + c)];
        }
        __syncthreads();
#pragma unroll
        for (int kk = 0; kk < 16; kk++) {
            float a[4], w[4];
#pragma unroll
            for (int i = 0; i < 4; i++) a[i] = Xs[ty * 4 + i][kk];
#pragma unroll
            for (int j = 0; j < 4; j++) w[j] = Ws[tx * 4 + j][kk];
#pragma unroll
            for (int i = 0; i < 4; i++)
#pragma unroll
                for (int j = 0; j < 4; j++)
                    acc[i][j] += a[i] * w[j];
        }
        __syncthreads();
    }
#pragma unroll
    for (int i = 0; i < 4; i++) {
        int m = m0 + ty * 4 + i;
#pragma unroll
        for (int j = 0; j < 4; j++) {
            int n = n0 + tx * 4 + j;
            C[(size_t)m * N + n] = acc[i][j] + bias[n];
        }
    }
}

// ---------------- h[0] = h0 ----------------
__global__ __launch_bounds__(256) void copy_h0_kernel(
    const float* __restrict__ h0, float* __restrict__ h)
{
    int i = blockIdx.x * 256 + threadIdx.x;
    if (i < BATCH * DIM) h[i] = h0[i];
}

// ---------------- one recurrence step ----------------
// grid: 64 WGs; WG handles e-slice of 16 columns x all 16 batches.
// LDS: h_prev [16][1024] staged cooperatively.
__global__ __launch_bounds__(256) void rnn_step_kernel(
    const float* __restrict__ Wh,         // [D, D]
    const float* __restrict__ log_alpha,  // [1]
    float* __restrict__ outs,             // [T,B,D] (wx in, out overwritten)
    float* __restrict__ h,                // [T+1,B,D]
    int t)
{
    __shared__ float hs[BATCH][DIM];  // 64 KB
    const int tid = threadIdx.x;
    const float* hprev = h + (size_t)t * BATCH * DIM;

    // cooperative load of h_prev (16384 floats) as float4
    const float4* hp4 = (const float4*)hprev;
#pragma unroll
    for (int i = 0; i < 16; i++) {
        int idx = tid + i * 256;          // 0..4095 float4 index
        int b = idx >> 8;                 // 256 float4 per row
        int d4 = idx & 255;
        float4 v = hp4[idx];
        hs[b][d4 * 4 + 0] = v.x;
        hs[b][d4 * 4 + 1] = v.y;
        hs[b][d4 * 4 + 2] = v.z;
        hs[b][d4 * 4 + 3] = v.w;
    }
    __syncthreads();

    const float alpha = expf(log_alpha[0]);
    const int b = tid >> 4;                        // 0..15
    const int e = blockIdx.x * 16 + (tid & 15);    // output column

    const float4* wrow = (const float4*)(Wh + (size_t)e * DIM);
    float acc = 0.f;
#pragma unroll 4
    for (int d4 = 0; d4 < DIM / 4; d4++) {
        float4 w = wrow[d4];
        acc += hs[b][d4 * 4 + 0] * w.x;
        acc += hs[b][d4 * 4 + 1] * w.y;
        acc += hs[b][d4 * 4 + 2] * w.z;
        acc += hs[b][d4 * 4 + 3] * w.w;
    }

    const size_t idx = (size_t)t * BATCH * DIM + (size_t)b * DIM + e;
    const float pre = acc + outs[idx];
    const float hprev_be = hs[b][e];
    const float hnew = hprev_be + alpha * tanhf(pre);
    h[(size_t)(t + 1) * BATCH * DIM + (size_t)b * DIM + e] = hnew;
    const float sig = 1.f / (1.f + expf(-hnew));
    outs[idx] = hnew * hnew * sig;
}

extern "C" void kernel_launch(void* const* d_in, const int* in_sizes, int n_in,
                              void* d_out, int out_size, void* d_ws, size_t ws_size,
                              hipStream_t stream) {
    const float* x         = (const float*)d_in[0];  // [T,B,D]
    const float* h0        = (const float*)d_in[1];  // [B,D]
    const float* W_x       = (const float*)d_in[2];  // [D,D]
    const float* W_h       = (const float*)d_in[3];  // [D,D]
    const float* bias      = (const float*)d_in[4];  // [D]
    const float* log_alpha = (const float*)d_in[5];  // [1]

    float* outs = (float*)d_out;                               // [T,B,D]
    float* h    = (float*)d_out + (size_t)T_STEPS * BATCH * DIM;  // [T+1,B,D]

    // 1) Wx_all (+bias) -> outs region. M = T*B = 32768 rows.
    dim3 ggrid(32768 / 64, DIM / 64);
    gemm_wx_kernel<<<ggrid, 256, 0, stream>>>(x, W_x, bias, outs);

    // 2) h[0] = h0
    copy_h0_kernel<<<(BATCH * DIM + 255) / 256, 256, 0, stream>>>(h0, h);

    // 3) sequential scan
    for (int t = 0; t < T_STEPS; t++) {
        rnn_step_kernel<<<DIM / 16, 256, 0, stream>>>(W_h, log_alpha, outs, h, t);
    }
}

// Round 2
// 25871.112 us; speedup vs baseline: 2.5206x; 2.5206x over previous
//
#include <hip/hip_runtime.h>
#include <math.h>

// T=2048, B=16, D=1024
//   Wx_all[t,b,e] = sum_d x[t,b,d] * W_x[e,d] + b[e]
//   scan: pre = h @ W_h^T + wx_t ; h += alpha*tanh(pre) ; out = h^2 * sigmoid(h)
// d_out layout: outs [T,B,D] floats, then h [T+1,B,D] floats.
// outs region doubles as the Wx_all buffer (read wx[t], overwrite with out[t]).
//
// Round 2: persistent scan kernel. 128 WGs x 256 thr, 1 WG/CU (112.5 KB LDS).
// W_h rows resident in LDS for the whole scan; per-step grid barrier via
// two-level device-scope atomic counters in d_ws (init'd by a prior kernel).

#define T_STEPS 2048
#define BATCH 16
#define DIM 1024
#define NWG 128
#define E_PER_WG 8            // DIM / NWG columns per WG
#define HS_STRIDE 257         // float4 stride per 1024-float row (+16B pad)
#define RED_STRIDE 516        // floats per pos slot (512 + 4 pad)

// ---------------- GEMM: C[m,n] = sum_k X[m,k]*W[n,k] + bias[n] ----------------
__global__ __launch_bounds__(256) void gemm_wx_kernel(
    const float* __restrict__ X,     // [M, K]
    const float* __restrict__ W,     // [N, K]
    const float* __restrict__ bias,  // [N]
    float* __restrict__ C)           // [M, N]
{
    const int K = DIM, N = DIM;
    __shared__ float Xs[64][17];
    __shared__ float Ws[64][17];
    const int tid = threadIdx.x;
    const int m0 = blockIdx.x * 64;
    const int n0 = blockIdx.y * 64;
    const int ty = tid >> 4;
    const int tx = tid & 15;
    float acc[4][4] = {};

    for (int k0 = 0; k0 < K; k0 += 16) {
#pragma unroll
        for (int i = 0; i < 4; i++) {
            int idx = tid + i * 256;
            int r = idx >> 4;
            int c = idx & 15;
            Xs[r][c] = X[(size_t)(m0 + r) * K + (k0 + c)];
            Ws[r][c] = W[(size_t)(n0 + r) * K + (k0 + c)];
        }
        __syncthreads();
#pragma unroll
        for (int kk = 0; kk < 16; kk++) {
            float a[4], w[4];
#pragma unroll
            for (int i = 0; i < 4; i++) a[i] = Xs[ty * 4 + i][kk];
#pragma unroll
            for (int j = 0; j < 4; j++) w[j] = Ws[tx * 4 + j][kk];
#pragma unroll
            for (int i = 0; i < 4; i++)
#pragma unroll
                for (int j = 0; j < 4; j++)
                    acc[i][j] += a[i] * w[j];
        }
        __syncthreads();
    }
#pragma unroll
    for (int i = 0; i < 4; i++) {
        int m = m0 + ty * 4 + i;
#pragma unroll
        for (int j = 0; j < 4; j++) {
            int n = n0 + tx * 4 + j;
            C[(size_t)m * N + n] = acc[i][j] + bias[n];
        }
    }
}

// ---------------- h[0] = h0 ----------------
__global__ __launch_bounds__(256) void copy_h0_kernel(
    const float* __restrict__ h0, float* __restrict__ h)
{
    int i = blockIdx.x * 256 + threadIdx.x;
    if (i < BATCH * DIM) h[i] = h0[i];
}

// ---------------- barrier counter init (d_ws is poisoned each launch) --------
__global__ void barrier_init_kernel(unsigned int* bar)
{
    if (threadIdx.x < 512) bar[threadIdx.x] = 0u;
}

// ---------------- persistent scan ----------------
// WG wg owns output columns e in [wg*8, wg*8+8).
// Thread map (main loop): pos = tid&7 -> eg = pos&1 (e-half), bg = pos>>2*? :
//   eg = pos & 1, bg = pos >> 1 ; ks = tid >> 3 (32 k-slices of 32 k each,
//   strided: thread reads float4 #(ks + 32m), m=0..7).
// Each thread: 4x4 partial micro-tile (e rows eg*4+i, b rows bg*4+j).
// Reduction over ks via LDS, finishers = tid<128, one output (b,e) each.
__global__ __launch_bounds__(256, 1) void rnn_scan_kernel(
    const float* __restrict__ Wh,         // [D, D]
    const float* __restrict__ log_alpha,  // [1]
    float* __restrict__ outs,             // [T,B,D] (wx in, out overwritten)
    float* __restrict__ h,                // [T+1,B,D]
    unsigned int* __restrict__ bar)       // barrier counters (zeroed)
{
    __shared__ float4 whs4[E_PER_WG * HS_STRIDE];  // 32.9 KB
    __shared__ float4 hs4[BATCH * HS_STRIDE];      // 65.8 KB
    __shared__ float red[8 * RED_STRIDE];          // 16.5 KB

    const int tid = threadIdx.x;
    const int wg = blockIdx.x;
    const int e0 = wg * E_PER_WG;

    // ---- preload W_h rows for this WG (once) ----
    const float4* wh4 = (const float4*)Wh;
#pragma unroll
    for (int i = 0; i < 8; i++) {
        int idx = tid + i * 256;
        int r = idx >> 8, f = idx & 255;
        whs4[r * HS_STRIDE + f] = wh4[(size_t)(e0 + r) * 256 + f];
    }

    const float alpha = expf(log_alpha[0]);

    // main-loop thread map
    const int pos = tid & 7;
    const int eg = pos & 1;
    const int bg = pos >> 1;
    const int ks = tid >> 3;

    // finisher map (valid for tid < 128)
    const int f_el = tid & 7;
    const int f_b  = tid >> 3;
    const int f_eg = f_el >> 2, f_i = f_el & 3;
    const int f_bg = f_b >> 2,  f_j = f_b & 3;
    const int f_pos = f_eg + 2 * f_bg;
    const int rbase_rd = f_pos * RED_STRIDE + f_i * 4 + f_j;

    const float* hsF = (const float*)hs4;
    unsigned int root_target = 0u;

    for (int t = 0; t < T_STEPS; t++) {
        // ---- stage h[t] into LDS (64 KB, float4 coalesced) ----
        const float4* hp4 = (const float4*)(h + (size_t)t * (BATCH * DIM));
#pragma unroll
        for (int i = 0; i < 16; i++) {
            int idx = tid + i * 256;
            int b = idx >> 8, f = idx & 255;
            hs4[b * HS_STRIDE + f] = hp4[idx];
        }
        __syncthreads();  // (A) hs ready, whs ready (t==0)

        // ---- 4x4 micro-tile partials over this thread's k-slice ----
        float p[4][4] = {};
#pragma unroll
        for (int m = 0; m < 8; m++) {
            const int f4 = ks + m * 32;
            float4 w[4], hv[4];
#pragma unroll
            for (int i = 0; i < 4; i++) w[i] = whs4[(eg * 4 + i) * HS_STRIDE + f4];
#pragma unroll
            for (int j = 0; j < 4; j++) hv[j] = hs4[(bg * 4 + j) * HS_STRIDE + f4];
#pragma unroll
            for (int i = 0; i < 4; i++)
#pragma unroll
                for (int j = 0; j < 4; j++)
                    p[i][j] += w[i].x * hv[j].x + w[i].y * hv[j].y
                             + w[i].z * hv[j].z + w[i].w * hv[j].w;
        }

        // ---- write partials: red[pos][ks][i*4+j] ----
        {
            float4* red4 = (float4*)red;
            const int rbase4 = pos * (RED_STRIDE / 4) + ks * 4;
#pragma unroll
            for (int i = 0; i < 4; i++)
                red4[rbase4 + i] = make_float4(p[i][0], p[i][1], p[i][2], p[i][3]);
        }
        __syncthreads();  // (B) partials visible

        // ---- finish: reduce over ks, nonlinearity, write h[t+1] & out[t] ----
        if (tid < 128) {
            float s = 0.f;
#pragma unroll
            for (int k2 = 0; k2 < 32; k2++) s += red[rbase_rd + k2 * 16];
            const int e = e0 + f_el;
            const size_t oidx = (size_t)t * (BATCH * DIM) + (size_t)f_b * DIM + e;
            const float pre = s + outs[oidx];
            const float hprev = hsF[f_b * (HS_STRIDE * 4) + e];
            const float hnew = hprev + alpha * tanhf(pre);
            h[(size_t)(t + 1) * (BATCH * DIM) + (size_t)f_b * DIM + e] = hnew;
            const float sig = 1.f / (1.f + expf(-hnew));
            outs[oidx] = hnew * hnew * sig;
        }
        __syncthreads();  // (C) drains stores (vmcnt 0) + hs/red reads done

        // ---- grid barrier (two-level, monotone counters) ----
        if (t + 1 < T_STEPS) {
            if (tid == 0) {
                __threadfence();  // release: write back L2 (agent scope)
                unsigned int old = __hip_atomic_fetch_add(
                    &bar[(wg & 7) * 32], 1u, __ATOMIC_ACQ_REL, __HIP_MEMORY_SCOPE_AGENT);
                if ((old & 15u) == 15u) {  // last of 16 in group this step
                    __hip_atomic_fetch_add(
                        &bar[256], 1u, __ATOMIC_ACQ_REL, __HIP_MEMORY_SCOPE_AGENT);
                }
                root_target += 8u;
                while (__hip_atomic_load(&bar[256], __ATOMIC_RELAXED,
                                         __HIP_MEMORY_SCOPE_AGENT) < root_target)
                    __builtin_amdgcn_s_sleep(1);
                __threadfence();  // acquire: invalidate L1/L2 before h[t+1] reads
            }
            __syncthreads();  // (D)
        }
    }
}

extern "C" void kernel_launch(void* const* d_in, const int* in_sizes, int n_in,
                              void* d_out, int out_size, void* d_ws, size_t ws_size,
                              hipStream_t stream) {
    const float* x         = (const float*)d_in[0];  // [T,B,D]
    const float* h0        = (const float*)d_in[1];  // [B,D]
    const float* W_x       = (const float*)d_in[2];  // [D,D]
    const float* W_h       = (const float*)d_in[3];  // [D,D]
    const float* bias      = (const float*)d_in[4];  // [D]
    const float* log_alpha = (const float*)d_in[5];  // [1]

    float* outs = (float*)d_out;                                  // [T,B,D]
    float* h    = (float*)d_out + (size_t)T_STEPS * BATCH * DIM;  // [T+1,B,D]
    unsigned int* bar = (unsigned int*)d_ws;

    // 1) Wx_all (+bias) -> outs region. M = T*B = 32768 rows.
    dim3 ggrid(32768 / 64, DIM / 64);
    gemm_wx_kernel<<<ggrid, 256, 0, stream>>>(x, W_x, bias, outs);

    // 2) h[0] = h0 ; barrier counters = 0
    copy_h0_kernel<<<(BATCH * DIM + 255) / 256, 256, 0, stream>>>(h0, h);
    barrier_init_kernel<<<1, 512, 0, stream>>>(bar);

    // 3) persistent scan
    rnn_scan_kernel<<<NWG, 256, 0, stream>>>(W_h, log_alpha, outs, h, bar);
}